// Round 9
// baseline (140.026 us; speedup 1.0000x reference)
//
#include <hip/hip_runtime.h>
#include <math.h>

#define NBINS 1000
#define NDIM 64
#define DIMS_PER_BLOCK 8
#define DIM_GROUPS (NDIM / DIMS_PER_BLOCK)      // 8
#define BLOCK_THREADS 1024
#define ROWS_PER_ITER (BLOCK_THREADS / 2)       // 512 rows per block-iteration
#define ROW_BLOCKS 64                            // 512 blocks = 2/CU, ALL resident
                                                 // (single generation). 64%8==0 ->
                                                 // all dim-groups of a row chunk on
                                                 // one XCD; partial-line merge OK
                                                 // (FETCH 38MB measured).
                                                 // STRUCTURE IS LOAD-BEARING (3x
                                                 // confirmed): no distant-row
                                                 // interleave (R3), no <32B per-row
                                                 // footprint (R5), no widened live
                                                 // row window (R7). Exactly 512
                                                 // consecutive rows per body.

typedef float f32x2 __attribute__((ext_vector_type(2)));

__device__ __forceinline__ f32x2 pk_fma(f32x2 a, f32x2 b, f32x2 c) {
    return __builtin_elementwise_fma(a, b, c);
}
__device__ __forceinline__ f32x2 pk_min(f32x2 a, f32x2 b) {
    return __builtin_elementwise_min(a, b);
}
__device__ __forceinline__ f32x2 pk_max(f32x2 a, f32x2 b) {
    return __builtin_elementwise_max(a, b);
}

// zero the log_det region (atomic fallback path only)
__global__ __launch_bounds__(1024) void mg_zero(float* __restrict__ p, int n) {
    int i = blockIdx.x * blockDim.x + threadIdx.x;
    if (i < n) p[i] = 0.0f;
}

// final reduce: log_det[row] = sum over 8 dim-group partials in ws
__global__ __launch_bounds__(256) void mg_reduce(const float* __restrict__ ws,
                                                 float* __restrict__ out, int B) {
    int row = blockIdx.x * blockDim.x + threadIdx.x;
    if (row >= B) return;
    float s = 0.0f;
#pragma unroll
    for (int g = 0; g < DIM_GROUPS; ++g) s += ws[(size_t)g * B + row];
    out[row] = s;
}

// Packed-pair math (2 dims at once) in e-space (tables store c' = 2c-1):
// interp, clamps, BOTH Horner chains, z and accumulators run as v_pk_*_f32
// (<2 x float> -> VOP3P on gfx950, 2x f32 issue rate). log/sqrt stay scalar
// (trans pipe, no packed form). Tail poly branchless-packed: it was wave-level
// ~74% taken anyway; always-compute removes exec-mask churn.
// The exact searchsorted fix-up walk stays scalar per element (rarely taken;
// compares STORED x knots -> bin selection exact). MACRO keeps knots[] a
// direct LDS access.
#define PAIR_MATH(x0_, x1_, base0_, base1_, i0_, i1_, a0_, b0_, a1_, b1_,         \
                  sc0_, sc1_, phpv_, ssv_, z0_, z1_)                              \
    {                                                                             \
        float xd0 = (x0_), xd1 = (x1_);                                           \
        int i0 = (i0_), i1 = (i1_);                                               \
        float2 a0 = (a0_), b0 = (b0_), a1 = (a1_), b1 = (b1_);                    \
        if (__builtin_expect((xd0 > b0.x && i0 < NBINS - 2) ||                    \
                             (xd0 <= a0.x && i0 > 0), 0)) {                       \
            while (xd0 > b0.x && i0 < NBINS - 2) {                                \
                ++i0; a0 = b0; b0 = knots[(base0_) + i0 + 1];                     \
            }                                                                     \
            while (xd0 <= a0.x && i0 > 0) {                                       \
                --i0; b0 = a0; a0 = knots[(base0_) + i0];                         \
            }                                                                     \
        }                                                                         \
        if (__builtin_expect((xd1 > b1.x && i1 < NBINS - 2) ||                    \
                             (xd1 <= a1.x && i1 > 0), 0)) {                       \
            while (xd1 > b1.x && i1 < NBINS - 2) {                                \
                ++i1; a1 = b1; b1 = knots[(base1_) + i1 + 1];                     \
            }                                                                     \
            while (xd1 <= a1.x && i1 > 0) {                                       \
                --i1; b1 = a1; a1 = knots[(base1_) + i1];                         \
            }                                                                     \
        }                                                                         \
        f32x2 xd = {xd0, xd1};                                                    \
        f32x2 ax = {a0.x, a1.x}, ay = {a0.y, a1.y};                               \
        f32x2 dy = {b0.y - a0.y, b1.y - a1.y};                                    \
        f32x2 sc = {(sc0_), (sc1_)};                                              \
        f32x2 slope2 = dy * sc;                 /* = 2*p_hat (const inv-step) */  \
        f32x2 e = pk_fma(slope2, xd - ax, ay);                                    \
        f32x2 ph2 = pk_max(slope2, (f32x2){2e-12f, 2e-12f});                      \
        f32x2 e1 = pk_min(pk_max(e, (f32x2){-0.99999f, -0.99999f}),               \
                          (f32x2){0.99999f, 0.99999f});                           \
        f32x2 m = pk_fma(-e1, e1, (f32x2){1.0f, 1.0f});                           \
        f32x2 wv = {(-0.6931471805599453f) * __builtin_amdgcn_logf(m.x),          \
                    (-0.6931471805599453f) * __builtin_amdgcn_logf(m.y)};         \
        f32x2 t = wv - 2.5f;                                                      \
        f32x2 p = {2.81022636e-08f, 2.81022636e-08f};                             \
        p = pk_fma(p, t, (f32x2){3.43273939e-07f, 3.43273939e-07f});              \
        p = pk_fma(p, t, (f32x2){-3.5233877e-06f, -3.5233877e-06f});              \
        p = pk_fma(p, t, (f32x2){-4.39150654e-06f, -4.39150654e-06f});            \
        p = pk_fma(p, t, (f32x2){0.00021858087f, 0.00021858087f});                \
        p = pk_fma(p, t, (f32x2){-0.00125372503f, -0.00125372503f});              \
        p = pk_fma(p, t, (f32x2){-0.00417768164f, -0.00417768164f});              \
        p = pk_fma(p, t, (f32x2){0.246640727f, 0.246640727f});                    \
        p = pk_fma(p, t, (f32x2){1.50140941f, 1.50140941f});                      \
        f32x2 tq = {__builtin_sqrtf(wv.x), __builtin_sqrtf(wv.y)};                \
        tq = tq - 3.0f;                                                           \
        f32x2 pt = {-0.000200214257f, -0.000200214257f};                          \
        pt = pk_fma(pt, tq, (f32x2){0.000100950558f, 0.000100950558f});           \
        pt = pk_fma(pt, tq, (f32x2){0.00134934322f, 0.00134934322f});             \
        pt = pk_fma(pt, tq, (f32x2){-0.00367342844f, -0.00367342844f});           \
        pt = pk_fma(pt, tq, (f32x2){0.00573950773f, 0.00573950773f});             \
        pt = pk_fma(pt, tq, (f32x2){-0.0076224613f, -0.0076224613f});             \
        pt = pk_fma(pt, tq, (f32x2){0.00943887047f, 0.00943887047f});             \
        pt = pk_fma(pt, tq, (f32x2){1.00167406f, 1.00167406f});                   \
        pt = pk_fma(pt, tq, (f32x2){2.83297682f, 2.83297682f});                   \
        f32x2 ps = {wv.x >= 5.0f ? pt.x : p.x, wv.y >= 5.0f ? pt.y : p.y};        \
        f32x2 z = (ps * e1) * 1.4142135623730951f; /* |z|<=4.418, clamp dead */   \
        (z0_) = z.x;                                                              \
        (z1_) = z.y;                                                              \
        (ssv_) = pk_fma(z, z, (ssv_));                                            \
        (phpv_) = (phpv_) * ph2;                                                  \
    }

// float-domain clamp-to-[0,998] via single v_med3_f32, then convert.
__device__ __forceinline__ int bin_guess(float xv, float sc, float bi) {
    return (int)__builtin_amdgcn_fmed3f(fmaf(xv, sc, bi), 0.0f,
                                        (float)(NBINS - 2));
}

// lane0<->lane1 pair swap as pure VALU (DPP quad_perm [1,0,3,2] = 0xB1).
// No lgkm event -> the reduce never drains outstanding LDS gathers (R6 win).
__device__ __forceinline__ float pair_swap_dpp(float v) {
    return __int_as_float(__builtin_amdgcn_update_dpp(
        __float_as_int(v), __float_as_int(v), 0xB1, 0xF, 0xF, true));
}

// Block owns 8 dims; knots (x_i, 2c_i-1) staged in LDS (64 KB).
// MEMORY STRUCTURE = R6 verbatim (measured best; FETCH 38MB, WRITE 90MB).
// Pipeline per body k: issue x(k+2) -> math(k) [gathers issued in body k-1,
// full body of lgkm slack] -> bins+gathers(k+1) from x(k+1) [arrived: issued
// 2 bodies ago] -> stores + DPP reduce [no lgkm wait].
template <bool USE_WS>
__global__ __launch_bounds__(BLOCK_THREADS, 8)
void mg_main(const float* __restrict__ x,
             const float* __restrict__ xvals,
             const float* __restrict__ cdf,
             float* __restrict__ out, float* __restrict__ ws, int B) {
    __shared__ float2 knots[DIMS_PER_BLOCK * NBINS];   // 64000 B

    const int dimbase = blockIdx.y * DIMS_PER_BLOCK;

    {   // vectorized stage: 2000 float4s from each table; c -> 2c-1 (e-space)
        const float4* xv4 = (const float4*)(xvals + (size_t)dimbase * NBINS);
        const float4* cd4 = (const float4*)(cdf + (size_t)dimbase * NBINS);
        for (int k = threadIdx.x; k < DIMS_PER_BLOCK * NBINS / 4; k += BLOCK_THREADS) {
            float4 a = xv4[k], c = cd4[k];
            knots[k * 4 + 0] = make_float2(a.x, fmaf(2.0f, c.x, -1.0f));
            knots[k * 4 + 1] = make_float2(a.y, fmaf(2.0f, c.y, -1.0f));
            knots[k * 4 + 2] = make_float2(a.z, fmaf(2.0f, c.z, -1.0f));
            knots[k * 4 + 3] = make_float2(a.w, fmaf(2.0f, c.w, -1.0f));
        }
    }
    __syncthreads();

    const int dl = (threadIdx.x & 1) * 4;                // local dims dl..dl+3
    const int qidx = blockIdx.y * 2 + (threadIdx.x & 1); // float4 index within row

    float scale[4], bias[4];
#pragma unroll
    for (int j = 0; j < 4; ++j) {
        float l = knots[(dl + j) * NBINS].x;
        float h = knots[(dl + j) * NBINS + NBINS - 1].x;
        float s = (float)(NBINS - 1) / (h - l);          // == 1/step_d
        scale[j] = s;
        bias[j] = -l * s;
    }

    const int rstride = gridDim.x * ROWS_PER_ITER;
    int row = blockIdx.x * ROWS_PER_ITER + (threadIdx.x >> 1);

    // prologue: x for iter 0 and 1; bins+gathers for iter 0
    float4 xq = make_float4(0.f, 0.f, 0.f, 0.f);
    float4 xn = make_float4(0.f, 0.f, 0.f, 0.f);
    if (row < B) xq = ((const float4*)x)[(size_t)row * (NDIM / 4) + qidx];
    if (row + rstride < B)
        xn = ((const float4*)x)[(size_t)(row + rstride) * (NDIM / 4) + qidx];

    int ii[4];
    float2 kl[4], kr[4];
    {
        float xv[4] = {xq.x, xq.y, xq.z, xq.w};
#pragma unroll
        for (int j = 0; j < 4; ++j) ii[j] = bin_guess(xv[j], scale[j], bias[j]);
#pragma unroll
        for (int j = 0; j < 4; ++j) {
            kl[j] = knots[(dl + j) * NBINS + ii[j]];
            kr[j] = knots[(dl + j) * NBINS + ii[j] + 1];
        }
    }

    for (; row < B; row += rstride) {
        // issue x(k+2): consumed by bins+gathers two bodies from now
        const int prow = row + 2 * rstride;
        float4 xn2 = make_float4(0.f, 0.f, 0.f, 0.f);
        if (prow < B) xn2 = ((const float4*)x)[(size_t)prow * (NDIM / 4) + qidx];

        // math on current row: gathers issued LAST body, full body of slack
        float z4[4];
        f32x2 phpv = {1.0f, 1.0f}, ssv = {0.0f, 0.0f};
        PAIR_MATH(xq.x, xq.y, (dl + 0) * NBINS, (dl + 1) * NBINS, ii[0], ii[1],
                  kl[0], kr[0], kl[1], kr[1], scale[0], scale[1],
                  phpv, ssv, z4[0], z4[1]);
        PAIR_MATH(xq.z, xq.w, (dl + 2) * NBINS, (dl + 3) * NBINS, ii[2], ii[3],
                  kl[2], kr[2], kl[3], kr[3], scale[2], scale[3],
                  phpv, ssv, z4[2], z4[3]);
        float sumsq = ssv.x + ssv.y;
        float php = phpv.x * phpv.y;

        // bins + gathers for NEXT body from xn (loaded 2 bodies ago, no vm wait)
        {
            float xv[4] = {xn.x, xn.y, xn.z, xn.w};
#pragma unroll
            for (int j = 0; j < 4; ++j)
                ii[j] = bin_guess(xv[j], scale[j], bias[j]);  // safe for dummy 0
#pragma unroll
            for (int j = 0; j < 4; ++j) {
                kl[j] = knots[(dl + j) * NBINS + ii[j]];
                kr[j] = knots[(dl + j) * NBINS + ii[j] + 1];
            }
        }

        ((float4*)out)[(size_t)row * (NDIM / 4) + qidx] =
            make_float4(z4[0], z4[1], z4[2], z4[3]);

        // term = sum_j [log(p_hat_j) + 0.5 z^2 + log(sqrt(2pi))], p_hat=slope2/2:
        // const = 4*(ln(sqrt(2pi)) - ln2) = 4*0.22579135264472744
        float term = fmaf(0.5f, sumsq, 4.0f * 0.22579135264472744f) +
                     0.6931471805599453f * __builtin_amdgcn_logf(php);

        term += pair_swap_dpp(term);       // partner lane covers the other 4 dims
        if ((threadIdx.x & 1) == 0) {
            if constexpr (USE_WS)
                ws[(size_t)blockIdx.y * B + row] = term;   // coalesced partial
            else
                atomicAdd(out + (size_t)B * NDIM + row, term);
        }

        xq = xn;
        xn = xn2;
    }
}

extern "C" void kernel_launch(void* const* d_in, const int* in_sizes, int n_in,
                              void* d_out, int out_size, void* d_ws, size_t ws_size,
                              hipStream_t stream) {
    const float* x = (const float*)d_in[0];
    const float* xvals = (const float*)d_in[1];
    const float* cdf = (const float*)d_in[2];
    float* out = (float*)d_out;
    int B = in_sizes[0] / NDIM;

    const size_t ws_need = (size_t)DIM_GROUPS * B * sizeof(float);
    dim3 grid(ROW_BLOCKS, DIM_GROUPS);

    if (ws_size >= ws_need) {
        float* ws = (float*)d_ws;
        hipLaunchKernelGGL((mg_main<true>), grid, dim3(BLOCK_THREADS), 0, stream,
                           x, xvals, cdf, out, ws, B);
        hipLaunchKernelGGL(mg_reduce, dim3((B + 255) / 256), dim3(256), 0, stream,
                           ws, out + (size_t)B * NDIM, B);
    } else {
        hipLaunchKernelGGL(mg_zero, dim3((B + 1023) / 1024), dim3(1024), 0, stream,
                           out + (size_t)B * NDIM, B);
        hipLaunchKernelGGL((mg_main<false>), grid, dim3(BLOCK_THREADS), 0, stream,
                           x, xvals, cdf, out, (float*)nullptr, B);
    }
}

// Round 10
// 139.545 us; speedup vs baseline: 1.0034x; 1.0034x over previous
//
#include <hip/hip_runtime.h>
#include <math.h>

#define NBINS 1000
#define NDIM 64
#define DIMS_PER_BLOCK 8
#define DIM_GROUPS (NDIM / DIMS_PER_BLOCK)      // 8
#define BLOCK_THREADS 1024
#define ROWS_PER_ITER (BLOCK_THREADS / 2)       // 512 rows per block-iteration
#define ROW_BLOCKS 64                            // 512 blocks = 2/CU, ALL resident
                                                 // (single generation). 64%8==0 ->
                                                 // all dim-groups of a row chunk on
                                                 // one XCD; partial-line merge OK
                                                 // (FETCH 38MB measured).
                                                 // STRUCTURE IS LOAD-BEARING (3x
                                                 // confirmed): no distant-row
                                                 // interleave (R3), no <32B per-row
                                                 // footprint (R5), no widened live
                                                 // row window (R7). Exactly 512
                                                 // consecutive rows per body.

typedef float f32x4v __attribute__((ext_vector_type(4)));

// zero the log_det region (atomic fallback path only)
__global__ __launch_bounds__(1024) void mg_zero(float* __restrict__ p, int n) {
    int i = blockIdx.x * blockDim.x + threadIdx.x;
    if (i < n) p[i] = 0.0f;
}

// final reduce: log_det[row] = sum over 8 dim-group partials in ws
__global__ __launch_bounds__(256) void mg_reduce(const float* __restrict__ ws,
                                                 float* __restrict__ out, int B) {
    int row = blockIdx.x * blockDim.x + threadIdx.x;
    if (row >= B) return;
    float s = 0.0f;
#pragma unroll
    for (int g = 0; g < DIM_GROUPS; ++g) s += ws[(size_t)g * B + row];
    out[row] = s;
}

// ONE instruction for the adjacent knot pair: (x_i, c_i, x_{i+1}, c_{i+1}).
// byte_off is the LDS byte offset (knots is the ONLY __shared__ object in
// mg_main -> it sits at LDS offset 0, so offset = elem_index * 8).
// offset0/1 units are 8B words for ds_read2_b64.
__device__ __forceinline__ f32x4v lds_pair_read(unsigned byte_off) {
    f32x4v q;
    asm volatile("ds_read2_b64 %0, %1 offset0:0 offset1:1"
                 : "=v"(q) : "v"(byte_off));
    return q;
}

// R6 per-dim math (measured best), walk REMOVED from the macro (hoisted into
// one fused cold branch per body). a/b must already be the exact bracket.
#define DIM_MATH(xd_, a_, b_, sc_, php_, ss_, zout_)                              \
    {                                                                             \
        float xd = (xd_);                                                         \
        float2 a = (a_), b = (b_);                                                \
        float slope = (b.y - a.y) * (sc_);   /* per-dim const inv-step */         \
        float u = fmaf(slope, xd - a.x, a.y);                                     \
        float ph = fmaxf(slope, 1e-12f);                                          \
        float e1 = fminf(fmaxf(fmaf(2.0f, u, -1.0f), -0.99999f), 0.99999f);       \
        float wv = -0.6931471805599453f *                                         \
                   __builtin_amdgcn_logf(fmaf(-e1, e1, 1.0f));                    \
        float t = wv - 2.5f;                                                      \
        float p = 2.81022636e-08f;                                                \
        p = fmaf(p, t, 3.43273939e-07f);                                          \
        p = fmaf(p, t, -3.5233877e-06f);                                          \
        p = fmaf(p, t, -4.39150654e-06f);                                         \
        p = fmaf(p, t, 0.00021858087f);                                           \
        p = fmaf(p, t, -0.00125372503f);                                          \
        p = fmaf(p, t, -0.00417768164f);                                          \
        p = fmaf(p, t, 0.246640727f);                                             \
        p = fmaf(p, t, 1.50140941f);                                              \
        if (wv >= 5.0f) {                                                         \
            float tq = sqrtf(wv) - 3.0f;                                          \
            float pt = -0.000200214257f;                                          \
            pt = fmaf(pt, tq, 0.000100950558f);                                   \
            pt = fmaf(pt, tq, 0.00134934322f);                                    \
            pt = fmaf(pt, tq, -0.00367342844f);                                   \
            pt = fmaf(pt, tq, 0.00573950773f);                                    \
            pt = fmaf(pt, tq, -0.0076224613f);                                    \
            pt = fmaf(pt, tq, 0.00943887047f);                                    \
            pt = fmaf(pt, tq, 1.00167406f);                                       \
            pt = fmaf(pt, tq, 2.83297682f);                                       \
            p = pt;                                                               \
        }                                                                         \
        float z = 1.4142135623730951f * p * e1; /* |z|<=4.418, ref clamp dead */  \
        (zout_) = z;                                                              \
        (ss_) = fmaf(z, z, (ss_));                                                \
        (php_) *= ph;                                                             \
    }

// lane0<->lane1 pair swap as pure VALU (DPP quad_perm [1,0,3,2] = 0xB1).
// No lgkm event -> the reduce never drains outstanding LDS gathers (R6 win).
__device__ __forceinline__ float pair_swap_dpp(float v) {
    return __int_as_float(__builtin_amdgcn_update_dpp(
        __float_as_int(v), __float_as_int(v), 0xB1, 0xF, 0xF, true));
}

// Block owns 8 dims; knots (x_i,c_i) staged in LDS (64 KB, offset 0).
// MEMORY STRUCTURE = R6 verbatim (measured best: 47.3us, FETCH 38MB).
// Pipeline per body k: issue x(k+2) -> lgkmcnt(0)+sched_barrier -> unpack
// quads (issued in body k-1) -> ONE fused cold guard (exact searchsorted
// walks, ~5% of wave-bodies) -> math(k) -> bins + ds_read2 gathers(k+1)
// from x(k+1) [arrived: issued 2 bodies ago] -> stores + DPP reduce.
template <bool USE_WS>
__global__ __launch_bounds__(BLOCK_THREADS, 8)
void mg_main(const float* __restrict__ x,
             const float* __restrict__ xvals,
             const float* __restrict__ cdf,
             float* __restrict__ out, float* __restrict__ ws, int B) {
    __shared__ float2 knots[DIMS_PER_BLOCK * NBINS];   // 64000 B @ LDS offset 0

    const int dimbase = blockIdx.y * DIMS_PER_BLOCK;

    {   // vectorized stage: 2000 float4s from each table
        const float4* xv4 = (const float4*)(xvals + (size_t)dimbase * NBINS);
        const float4* cd4 = (const float4*)(cdf + (size_t)dimbase * NBINS);
        for (int k = threadIdx.x; k < DIMS_PER_BLOCK * NBINS / 4; k += BLOCK_THREADS) {
            float4 a = xv4[k], c = cd4[k];
            knots[k * 4 + 0] = make_float2(a.x, c.x);
            knots[k * 4 + 1] = make_float2(a.y, c.y);
            knots[k * 4 + 2] = make_float2(a.z, c.z);
            knots[k * 4 + 3] = make_float2(a.w, c.w);
        }
    }
    __syncthreads();

    const int dl = (threadIdx.x & 1) * 4;                // local dims dl..dl+3
    const int qidx = blockIdx.y * 2 + (threadIdx.x & 1); // float4 index within row

    float scale[4], bias[4];
    unsigned kbase[4];                                   // LDS byte base per dim
#pragma unroll
    for (int j = 0; j < 4; ++j) {
        float l = knots[(dl + j) * NBINS].x;
        float h = knots[(dl + j) * NBINS + NBINS - 1].x;
        float s = (float)(NBINS - 1) / (h - l);          // == 1/step_d
        scale[j] = s;
        bias[j] = -l * s;
        kbase[j] = (unsigned)((dl + j) * NBINS) * 8u;
    }

    const int rstride = gridDim.x * ROWS_PER_ITER;
    int row = blockIdx.x * ROWS_PER_ITER + (threadIdx.x >> 1);

    // prologue: x for iter 0 and 1; bins+gathers for iter 0
    float4 xq = make_float4(0.f, 0.f, 0.f, 0.f);
    float4 xn = make_float4(0.f, 0.f, 0.f, 0.f);
    if (row < B) xq = ((const float4*)x)[(size_t)row * (NDIM / 4) + qidx];
    if (row + rstride < B)
        xn = ((const float4*)x)[(size_t)(row + rstride) * (NDIM / 4) + qidx];

    int ii[4];
    f32x4v qd[4];
    {
        float xv[4] = {xq.x, xq.y, xq.z, xq.w};
#pragma unroll
        for (int j = 0; j < 4; ++j) {
            int i = (int)fmaf(xv[j], scale[j], bias[j]);
            ii[j] = min(max(i, 0), NBINS - 2);
        }
#pragma unroll
        for (int j = 0; j < 4; ++j)
            qd[j] = lds_pair_read(kbase[j] + ((unsigned)ii[j] << 3));
    }

    for (; row < B; row += rstride) {
        // issue x(k+2): consumed by bins+gathers two bodies from now
        const int prow = row + 2 * rstride;
        float4 xn2 = make_float4(0.f, 0.f, 0.f, 0.f);
        if (prow < B) xn2 = ((const float4*)x)[(size_t)prow * (NDIM / 4) + qidx];

        // wait for the quads issued LAST body (only lgkm producers in flight);
        // sched_barrier stops the compiler hoisting their uses above the wait
        // (rule #18: "memory" clobber does not order register-only consumers).
        asm volatile("s_waitcnt lgkmcnt(0)" ::: "memory");
        __builtin_amdgcn_sched_barrier(0);

        float xv[4] = {xq.x, xq.y, xq.z, xq.w};
        float2 ka[4], kb[4];
#pragma unroll
        for (int j = 0; j < 4; ++j) {
            ka[j] = make_float2(qd[j].x, qd[j].y);
            kb[j] = make_float2(qd[j].z, qd[j].w);
        }

        // ONE fused guard for all 4 dims (predicates from quad values);
        // cold body runs the exact searchsorted(side='left') walks.
        bool need = false;
#pragma unroll
        for (int j = 0; j < 4; ++j)
            need |= (xv[j] > kb[j].x && ii[j] < NBINS - 2) ||
                    (xv[j] <= ka[j].x && ii[j] > 0);
        if (__builtin_expect(need, 0)) {
#pragma unroll
            for (int j = 0; j < 4; ++j) {
                int i = ii[j];
                float2 a = ka[j], b = kb[j];
                const int base = (dl + j) * NBINS;
                while (xv[j] > b.x && i < NBINS - 2) {
                    ++i; a = b; b = knots[base + i + 1];
                }
                while (xv[j] <= a.x && i > 0) {
                    --i; b = a; a = knots[base + i];
                }
                ka[j] = a; kb[j] = b;
            }
        }

        // math on current row (bracket exact; no per-dim branches)
        float z4[4], php = 1.0f, sumsq = 0.0f;
        DIM_MATH(xv[0], ka[0], kb[0], scale[0], php, sumsq, z4[0]);
        DIM_MATH(xv[1], ka[1], kb[1], scale[1], php, sumsq, z4[1]);
        DIM_MATH(xv[2], ka[2], kb[2], scale[2], php, sumsq, z4[2]);
        DIM_MATH(xv[3], ka[3], kb[3], scale[3], php, sumsq, z4[3]);

        // bins + ds_read2 gathers for NEXT body from xn (loaded 2 bodies ago)
        {
            float xw[4] = {xn.x, xn.y, xn.z, xn.w};
#pragma unroll
            for (int j = 0; j < 4; ++j) {
                int i = (int)fmaf(xw[j], scale[j], bias[j]);
                ii[j] = min(max(i, 0), NBINS - 2);   // safe even for dummy xn=0
            }
#pragma unroll
            for (int j = 0; j < 4; ++j)
                qd[j] = lds_pair_read(kbase[j] + ((unsigned)ii[j] << 3));
        }

        ((float4*)out)[(size_t)row * (NDIM / 4) + qidx] =
            make_float4(z4[0], z4[1], z4[2], z4[3]);

        // term = sum_j [log(p_hat_j) + 0.5 z^2 + log(sqrt(2pi))]
        // -log(phi+1e-12) == 0.5 z^2 + 0.9189385 to 4.3e-8 abs since |z|<=4.418
        float term = fmaf(0.5f, sumsq, 4.0f * 0.9189385332046727f) +
                     0.6931471805599453f * __builtin_amdgcn_logf(php);

        term += pair_swap_dpp(term);       // partner lane covers the other 4 dims
        if ((threadIdx.x & 1) == 0) {
            if constexpr (USE_WS)
                ws[(size_t)blockIdx.y * B + row] = term;   // coalesced partial
            else
                atomicAdd(out + (size_t)B * NDIM + row, term);
        }

        xq = xn;
        xn = xn2;
    }
}

extern "C" void kernel_launch(void* const* d_in, const int* in_sizes, int n_in,
                              void* d_out, int out_size, void* d_ws, size_t ws_size,
                              hipStream_t stream) {
    const float* x = (const float*)d_in[0];
    const float* xvals = (const float*)d_in[1];
    const float* cdf = (const float*)d_in[2];
    float* out = (float*)d_out;
    int B = in_sizes[0] / NDIM;

    const size_t ws_need = (size_t)DIM_GROUPS * B * sizeof(float);
    dim3 grid(ROW_BLOCKS, DIM_GROUPS);

    if (ws_size >= ws_need) {
        float* ws = (float*)d_ws;
        hipLaunchKernelGGL((mg_main<true>), grid, dim3(BLOCK_THREADS), 0, stream,
                           x, xvals, cdf, out, ws, B);
        hipLaunchKernelGGL(mg_reduce, dim3((B + 255) / 256), dim3(256), 0, stream,
                           ws, out + (size_t)B * NDIM, B);
    } else {
        hipLaunchKernelGGL(mg_zero, dim3((B + 1023) / 1024), dim3(1024), 0, stream,
                           out + (size_t)B * NDIM, B);
        hipLaunchKernelGGL((mg_main<false>), grid, dim3(BLOCK_THREADS), 0, stream,
                           x, xvals, cdf, out, (float*)nullptr, B);
    }
}